// Round 1
// baseline (45.842 us; speedup 1.0000x reference)
//
#include <hip/hip_runtime.h>

// HybridSymmetricLoss: B=8192, P=4, M=12, 24 perms of 4 slots.
// Per batch: pairL[p][q] = sum_{i,j} BCE(assign[b,q,i,j], labels[b,p,i,j])
// loss(perm) = sum_p pairL[p][perm[p]]; min over 24 perms; argmin perm
// selects category columns for second BCE. Output = 1.0*mean(minloss) +
// 0.5*mean(catBCE).

__device__ __forceinline__ float clogf_(float x) {
    return fmaxf(logf(x), -100.0f);
}
__device__ __forceinline__ float clog1mf_(float x) {
    return fmaxf(log1pf(-x), -100.0f);
}

__global__ __launch_bounds__(256) void hsl_per_batch(
    const float* __restrict__ assign,    // [B,4,12,12]
    const float* __restrict__ cat,       // [B,4]
    const float* __restrict__ alabels,   // [B,4,12,12]
    const float* __restrict__ clabels,   // [B,4]
    float* __restrict__ ws_min,          // [B] per-batch min mean loss
    float* __restrict__ ws_cat,          // [B] per-batch category BCE sum
    int B)
{
    const int wave = (int)((blockIdx.x * blockDim.x + threadIdx.x) >> 6);
    const int lane = (int)(threadIdx.x & 63);
    if (wave >= B) return;
    const int b = wave;

    const float* __restrict__ A = assign  + (size_t)b * 576;
    const float* __restrict__ Y = alabels + (size_t)b * 576;

    // s[p*4+q] accumulates sum over elements of (y ? log(a) : log1p(-a))
    // (i.e. NEGATED BCE). min loss == max s.
    float s[16];
#pragma unroll
    for (int i = 0; i < 16; ++i) s[i] = 0.0f;

#pragma unroll
    for (int it = 0; it < 3; ++it) {
        const int e = lane + it * 64;
        if (e < 144) {
            float la[4], lb[4], y[4];
#pragma unroll
            for (int q = 0; q < 4; ++q) {
                const float a = A[q * 144 + e];
                la[q] = clogf_(a);
                lb[q] = clog1mf_(a);
            }
#pragma unroll
            for (int p = 0; p < 4; ++p) y[p] = Y[p * 144 + e];
#pragma unroll
            for (int p = 0; p < 4; ++p) {
                const bool yy = (y[p] != 0.0f);
#pragma unroll
                for (int q = 0; q < 4; ++q) {
                    s[p * 4 + q] += yy ? la[q] : lb[q];
                }
            }
        }
    }

    // butterfly reduce the 16 pair sums across the 64-lane wave
#pragma unroll
    for (int m = 1; m < 64; m <<= 1) {
#pragma unroll
        for (int i = 0; i < 16; ++i) {
            s[i] += __shfl_xor(s[i], m, 64);
        }
    }

    // 24 permutations, lexicographic (matches itertools.permutations).
    // argmin(loss) with first-index tie-break == argmax(score) with strict >.
    float best = -3.0e38f;
    unsigned bestBits = 0u;
#define TRYP(p0, p1, p2, p3)                                                  \
    {                                                                         \
        const float v = s[0 * 4 + (p0)] + s[1 * 4 + (p1)] +                   \
                        s[2 * 4 + (p2)] + s[3 * 4 + (p3)];                    \
        if (v > best) {                                                       \
            best = v;                                                         \
            bestBits = (unsigned)((p0) | ((p1) << 2) | ((p2) << 4) |          \
                                  ((p3) << 6));                               \
        }                                                                     \
    }
    TRYP(0,1,2,3) TRYP(0,1,3,2) TRYP(0,2,1,3) TRYP(0,2,3,1)
    TRYP(0,3,1,2) TRYP(0,3,2,1) TRYP(1,0,2,3) TRYP(1,0,3,2)
    TRYP(1,2,0,3) TRYP(1,2,3,0) TRYP(1,3,0,2) TRYP(1,3,2,0)
    TRYP(2,0,1,3) TRYP(2,0,3,1) TRYP(2,1,0,3) TRYP(2,1,3,0)
    TRYP(2,3,0,1) TRYP(2,3,1,0) TRYP(3,0,1,2) TRYP(3,0,2,1)
    TRYP(3,1,0,2) TRYP(3,1,2,0) TRYP(3,2,0,1) TRYP(3,2,1,0)
#undef TRYP

    if (lane == 0) {
        ws_min[b] = -best * (1.0f / 576.0f);

        const float* __restrict__ C  = cat     + (size_t)b * 4;
        const float* __restrict__ CY = clabels + (size_t)b * 4;
        float cs = 0.0f;
#pragma unroll
        for (int p = 0; p < 4; ++p) {
            const int q = (int)((bestBits >> (2 * p)) & 3u);
            const float c = C[q];
            const float yv = CY[p];
            const float l = (yv != 0.0f) ? clogf_(c) : clog1mf_(c);
            cs += -l;
        }
        ws_cat[b] = cs;
    }
}

__global__ __launch_bounds__(256) void hsl_reduce(
    const float* __restrict__ ws_min,
    const float* __restrict__ ws_cat,
    float* __restrict__ out,
    int B)
{
    __shared__ double smin[256];
    __shared__ double scat[256];
    double m = 0.0, c = 0.0;
    for (int i = (int)threadIdx.x; i < B; i += 256) {
        m += (double)ws_min[i];
        c += (double)ws_cat[i];
    }
    smin[threadIdx.x] = m;
    scat[threadIdx.x] = c;
    __syncthreads();
    for (int s = 128; s > 0; s >>= 1) {
        if ((int)threadIdx.x < s) {
            smin[threadIdx.x] += smin[threadIdx.x + s];
            scat[threadIdx.x] += scat[threadIdx.x + s];
        }
        __syncthreads();
    }
    if (threadIdx.x == 0) {
        const double assignments_loss = smin[0] / (double)B;
        const double category_loss = scat[0] / (double)(B * 4);
        out[0] = (float)(1.0 * assignments_loss + 0.5 * category_loss);
    }
}

extern "C" void kernel_launch(void* const* d_in, const int* in_sizes, int n_in,
                              void* d_out, int out_size, void* d_ws, size_t ws_size,
                              hipStream_t stream) {
    const float* assign  = (const float*)d_in[0];
    const float* cat     = (const float*)d_in[1];
    const float* alabels = (const float*)d_in[2];
    const float* clabels = (const float*)d_in[3];
    float* out = (float*)d_out;

    const int B = in_sizes[0] / 576;  // 8192

    float* ws_min = (float*)d_ws;
    float* ws_cat = ws_min + B;

    // one 64-lane wave per batch, 4 waves per block
    const int waves_per_block = 4;
    const int blocks = (B + waves_per_block - 1) / waves_per_block;
    hipLaunchKernelGGL(hsl_per_batch, dim3(blocks), dim3(256), 0, stream,
                       assign, cat, alabels, clabels, ws_min, ws_cat, B);
    hipLaunchKernelGGL(hsl_reduce, dim3(1), dim3(256), 0, stream,
                       ws_min, ws_cat, out, B);
}

// Round 2
// 16.336 us; speedup vs baseline: 2.8062x; 2.8062x over previous
//
#include <hip/hip_runtime.h>
#include <math.h>

// HybridSymmetricLoss: B=8192, P=4, M=12, 24 perms of 4 slots.
// pairL[p][q] = sum_{i,j} BCE(assign[b,q,:,:], labels[b,p,:,:])
// loss(perm) = sum_p pairL[p][perm[p]]; min/argmin over 24 perms;
// argmin perm permutes category for second BCE.
// All logs kept in log2 domain (v_log_f32), scaled by ln2 once.

#define LOG2_CLIP (-144.26950408889634f)   // -100 / ln(2)
#define LN2F      (0.6931471805599453f)

// Packed gather-lane table, lexicographic perms. byte p = 16*p + 4*sigma(p)
// (= source lane holding total s[4*p + sigma(p)] after reduce-scatter).
#define PK(a,b,c,d) ((unsigned)((4u*(a)) | ((16u+4u*(b))<<8) | \
                                ((32u+4u*(c))<<16) | ((48u+4u*(d))<<24)))
__device__ const unsigned PERM_PK[32] = {
    PK(0,1,2,3), PK(0,1,3,2), PK(0,2,1,3), PK(0,2,3,1), PK(0,3,1,2), PK(0,3,2,1),
    PK(1,0,2,3), PK(1,0,3,2), PK(1,2,0,3), PK(1,2,3,0), PK(1,3,0,2), PK(1,3,2,0),
    PK(2,0,1,3), PK(2,0,3,1), PK(2,1,0,3), PK(2,1,3,0), PK(2,3,0,1), PK(2,3,1,0),
    PK(3,0,1,2), PK(3,0,2,1), PK(3,1,0,2), PK(3,1,2,0), PK(3,2,0,1), PK(3,2,1,0),
    // padding (never selected: their scores are forced to -inf)
    PK(0,1,2,3), PK(0,1,2,3), PK(0,1,2,3), PK(0,1,2,3),
    PK(0,1,2,3), PK(0,1,2,3), PK(0,1,2,3), PK(0,1,2,3)
};

__global__ __launch_bounds__(256) void hsl_per_batch(
    const float* __restrict__ assign,    // [B,4,12,12]
    const float* __restrict__ cat,       // [B,4]
    const float* __restrict__ alabels,   // [B,4,12,12]
    const float* __restrict__ clabels,   // [B,4]
    float* __restrict__ ws,              // [B] per-batch combined contribution
    int B)
{
    const int wave = (int)((blockIdx.x * blockDim.x + threadIdx.x) >> 6);
    const int lane = (int)(threadIdx.x & 63);
    if (wave >= B) return;
    const int b = wave;

    const float* __restrict__ A = assign  + (size_t)b * 576;
    const float* __restrict__ Y = alabels + (size_t)b * 576;

    // s[4p+q] = sum_e y[p]*(la[q]-lb[q])   (log2 domain, negated BCE)
    // T[q]    = sum_e lb[q]
    float s[16], T[4];
#pragma unroll
    for (int i = 0; i < 16; ++i) s[i] = 0.0f;
#pragma unroll
    for (int i = 0; i < 4; ++i) T[i] = 0.0f;

#pragma unroll
    for (int it = 0; it < 3; ++it) {
        if (it < 2 || lane < 16) {       // e = lane + 64*it < 144
            const int e = lane + it * 64;
            float d[4], y[4];
#pragma unroll
            for (int q = 0; q < 4; ++q) {
                const float a  = A[q * 144 + e];
                const float la = fmaxf(__log2f(a),        LOG2_CLIP);
                const float lb = fmaxf(__log2f(1.0f - a), LOG2_CLIP);
                d[q] = la - lb;
                T[q] += lb;
            }
#pragma unroll
            for (int p = 0; p < 4; ++p) y[p] = Y[p * 144 + e];
#pragma unroll
            for (int p = 0; p < 4; ++p)
#pragma unroll
                for (int q = 0; q < 4; ++q)
                    s[p * 4 + q] = fmaf(y[p], d[q], s[p * 4 + q]);
        }
    }
    // fold T into s (sum over lanes of (s + T) == total y*d + total lb)
#pragma unroll
    for (int i = 0; i < 16; ++i) s[i] += T[i & 3];

    // ---- reduce-scatter butterfly: after 4 split stages lane l holds
    // partial of s[l>>2]; 2 more stages complete the 64-lane sum. ----
    const bool h32 = (lane & 32) != 0;
    const bool h16 = (lane & 16) != 0;
    const bool h8  = (lane & 8)  != 0;
    const bool h4  = (lane & 4)  != 0;

    float t[8];
#pragma unroll
    for (int i = 0; i < 8; ++i) {
        const float keep = h32 ? s[i + 8] : s[i];
        const float send = h32 ? s[i]     : s[i + 8];
        t[i] = keep + __shfl_xor(send, 32, 64);
    }
    float u[4];
#pragma unroll
    for (int i = 0; i < 4; ++i) {
        const float keep = h16 ? t[i + 4] : t[i];
        const float send = h16 ? t[i]     : t[i + 4];
        u[i] = keep + __shfl_xor(send, 16, 64);
    }
    float w[2];
#pragma unroll
    for (int i = 0; i < 2; ++i) {
        const float keep = h8 ? u[i + 2] : u[i];
        const float send = h8 ? u[i]     : u[i + 2];
        w[i] = keep + __shfl_xor(send, 8, 64);
    }
    float x;
    {
        const float keep = h4 ? w[1] : w[0];
        const float send = h4 ? w[0] : w[1];
        x = keep + __shfl_xor(send, 4, 64);
    }
    x += __shfl_xor(x, 2, 64);
    x += __shfl_xor(x, 1, 64);
    // now: x on lane l == total s[l >> 2]

    // ---- perm-parallel scoring: lane j < 24 evaluates perm j ----
    unsigned pk = PERM_PK[lane & 31];
    const float v0 = __shfl(x, (int)( pk        & 0xFFu), 64);
    const float v1 = __shfl(x, (int)((pk >> 8)  & 0xFFu), 64);
    const float v2 = __shfl(x, (int)((pk >> 16) & 0xFFu), 64);
    const float v3 = __shfl(x, (int)( pk >> 24        ), 64);
    float score = (v0 + v1) + (v2 + v3);
    if (lane >= 24) score = -__builtin_huge_valf();

    // max-butterfly over lanes 0..31 (covers all 24 perms), carry pk
#pragma unroll
    for (int m = 16; m >= 1; m >>= 1) {
        const float    os  = __shfl_xor(score, m, 64);
        const unsigned opk = __shfl_xor(pk,    m, 64);
        const bool take = os > score;
        score = take ? os  : score;
        pk    = take ? opk : pk;
    }

    if (lane == 0) {
        // category BCE with winning perm: q_p = (byte_p >> 2) & 3
        const float* __restrict__ C  = cat     + (size_t)b * 4;
        const float* __restrict__ CY = clabels + (size_t)b * 4;
        float cs2 = 0.0f;
#pragma unroll
        for (int p = 0; p < 4; ++p) {
            const int q  = (int)((pk >> (8 * p + 2)) & 3u);
            const float c  = C[q];
            const float yv = CY[p];
            const float l2 = (yv != 0.0f) ? fmaxf(__log2f(c), LOG2_CLIP)
                                          : fmaxf(__log2f(1.0f - c), LOG2_CLIP);
            cs2 += l2;
        }
        // ws[b] = min_loss_b + 0.5 * catBCE_b/4
        //       = -ln2 * (score/576 + cs2/8)
        ws[b] = -LN2F * (score * (1.0f / 576.0f) + 0.125f * cs2);
    }
}

__global__ __launch_bounds__(256) void hsl_reduce(
    const float* __restrict__ ws,
    float* __restrict__ out,
    int B)
{
    __shared__ double sm[256];
    double acc = 0.0;
    const int n4 = B >> 2;
    const float4* __restrict__ w4 = (const float4*)ws;
    for (int i = (int)threadIdx.x; i < n4; i += 256) {
        const float4 v = w4[i];
        acc += (double)((v.x + v.y) + (v.z + v.w));
    }
    for (int i = (n4 << 2) + (int)threadIdx.x; i < B; i += 256)
        acc += (double)ws[i];
    sm[threadIdx.x] = acc;
    __syncthreads();
    for (int r = 128; r > 0; r >>= 1) {
        if ((int)threadIdx.x < r) sm[threadIdx.x] += sm[threadIdx.x + r];
        __syncthreads();
    }
    if (threadIdx.x == 0) out[0] = (float)(sm[0] / (double)B);
}

extern "C" void kernel_launch(void* const* d_in, const int* in_sizes, int n_in,
                              void* d_out, int out_size, void* d_ws, size_t ws_size,
                              hipStream_t stream) {
    const float* assign  = (const float*)d_in[0];
    const float* cat     = (const float*)d_in[1];
    const float* alabels = (const float*)d_in[2];
    const float* clabels = (const float*)d_in[3];
    float* out = (float*)d_out;

    const int B = in_sizes[0] / 576;  // 8192
    float* ws = (float*)d_ws;

    const int waves_per_block = 4;
    const int blocks = (B + waves_per_block - 1) / waves_per_block;
    hipLaunchKernelGGL(hsl_per_batch, dim3(blocks), dim3(256), 0, stream,
                       assign, cat, alabels, clabels, ws, B);
    hipLaunchKernelGGL(hsl_reduce, dim3(1), dim3(256), 0, stream,
                       ws, out, B);
}